// Round 1
// baseline (1057.301 us; speedup 1.0000x reference)
//
#include <hip/hip_runtime.h>

// ---------------------------------------------------------------------------
// GCN forward: deg/dis -> CSR build -> [GEMM -> aggregate(relu)] x2 -> GEMM+bias
//              -> segment-mean pool -> tiny head
// All fp32. Workspace layout (256B aligned slots):
//   cnt[N] | wofs[N] | gsum[64*128] | gcnt[64]   <- zeroed by one memset
//   dis[N] | rowstart[N+1] | part[1024] | csr_src[E] | csr_coef[E]
//   bufA[N*128] | bufB[N*128]
// ---------------------------------------------------------------------------

__global__ __launch_bounds__(256) void count_kernel(const int* __restrict__ dst,
                                                    int* __restrict__ cnt, int E) {
    int e = blockIdx.x * blockDim.x + threadIdx.x;
    if (e < E) atomicAdd(&cnt[dst[e]], 1);
}

__global__ __launch_bounds__(256) void dis_kernel(const int* __restrict__ cnt,
                                                  float* __restrict__ dis, int N) {
    int n = blockIdx.x * blockDim.x + threadIdx.x;
    if (n < N) dis[n] = rsqrtf(1.0f + (float)cnt[n]);
}

__global__ __launch_bounds__(256) void scan_partial_kernel(const int* __restrict__ cnt,
                                                           int* __restrict__ part, int N) {
    __shared__ int sdata[256];
    int b = blockIdx.x, t = threadIdx.x;
    int base = b * 1024;
    int s = 0;
#pragma unroll
    for (int i = 0; i < 4; ++i) {
        int idx = base + t * 4 + i;
        if (idx < N) s += cnt[idx];
    }
    sdata[t] = s;
    __syncthreads();
    for (int off = 128; off > 0; off >>= 1) {
        if (t < off) sdata[t] += sdata[t + off];
        __syncthreads();
    }
    if (t == 0) part[b] = sdata[0];
}

__global__ void scan_parts_kernel(int* __restrict__ part, int* __restrict__ rowstart,
                                  int NB, int N) {
    if (blockIdx.x == 0 && threadIdx.x == 0) {
        int run = 0;
        for (int i = 0; i < NB; ++i) { int v = part[i]; part[i] = run; run += v; }
        rowstart[N] = run;
    }
}

__global__ __launch_bounds__(256) void scan_final_kernel(const int* __restrict__ cnt,
                                                         const int* __restrict__ part,
                                                         int* __restrict__ rowstart, int N) {
    __shared__ int sdata[256];
    int b = blockIdx.x, t = threadIdx.x;
    int base = b * 1024;
    int v[4];
    int s = 0;
#pragma unroll
    for (int i = 0; i < 4; ++i) {
        int idx = base + t * 4 + i;
        v[i] = (idx < N) ? cnt[idx] : 0;
        s += v[i];
    }
    sdata[t] = s;
    __syncthreads();
    // inclusive scan (Hillis-Steele, read-all-then-write)
    for (int off = 1; off < 256; off <<= 1) {
        int tmp = 0;
        if (t >= off) tmp = sdata[t - off];
        __syncthreads();
        sdata[t] += tmp;
        __syncthreads();
    }
    int run = part[b] + sdata[t] - s;  // exclusive prefix for this thread
#pragma unroll
    for (int i = 0; i < 4; ++i) {
        int idx = base + t * 4 + i;
        if (idx < N) rowstart[idx] = run;
        run += v[i];
    }
}

__global__ __launch_bounds__(256) void fill_kernel(const int* __restrict__ src,
                                                   const int* __restrict__ dst,
                                                   const float* __restrict__ dis,
                                                   const int* __restrict__ rowstart,
                                                   int* __restrict__ wofs,
                                                   int* __restrict__ csr_src,
                                                   float* __restrict__ csr_coef, int E) {
    int e = blockIdx.x * blockDim.x + threadIdx.x;
    if (e >= E) return;
    int d = dst[e], s = src[e];
    int p = rowstart[d] + atomicAdd(&wofs[d], 1);
    csr_src[p] = s;
    csr_coef[p] = dis[s] * dis[d];
}

// --- tiled fp32 GEMM: C[M][NC] = X[M][K] @ W[K][NC] (+bias, optional relu) ---
template <int K, int NC>
__global__ __launch_bounds__(256) void gemm_kernel(const float* __restrict__ X,
                                                   const float* __restrict__ W,
                                                   const float* __restrict__ bias,
                                                   float* __restrict__ C, int M,
                                                   int applyRelu) {
    constexpr int CG = NC / 4;    // col groups of 4
    constexpr int RG = 256 / CG;  // row groups
    constexpr int RPT = 64 / RG;  // rows per thread
    __shared__ float4 XL4[64][9];       // 64 rows x 32 k-floats (pad to 36)
    __shared__ float4 WL4[32][CG];      // 32 k x NC cols
    int tid = threadIdx.x;
    int tx = tid % CG, ty = tid / CG;
    int rowBase = blockIdx.x * 64;
    float4 acc[RPT];
#pragma unroll
    for (int i = 0; i < RPT; ++i) acc[i] = make_float4(0.f, 0.f, 0.f, 0.f);

    for (int kk = 0; kk < K; kk += 32) {
        // stage X tile: 64 rows x 32 cols = 512 float4
#pragma unroll
        for (int q = 0; q < 2; ++q) {
            int li = q * 256 + tid;
            int r = li >> 3, c4 = li & 7;
            int gr = rowBase + r;
            if (gr >= M) gr = M - 1;
            XL4[r][c4] = *(const float4*)&X[(size_t)gr * K + kk + c4 * 4];
        }
        // stage W tile: 32 x NC
        constexpr int WPT = (32 * CG) / 256;
#pragma unroll
        for (int q = 0; q < WPT; ++q) {
            int li = q * 256 + tid;
            int k = li / CG, c4 = li % CG;
            WL4[k][c4] = *(const float4*)&W[(size_t)(kk + k) * NC + c4 * 4];
        }
        __syncthreads();
#pragma unroll
        for (int kq4 = 0; kq4 < 8; ++kq4) {
            float4 w0 = WL4[kq4 * 4 + 0][tx];
            float4 w1 = WL4[kq4 * 4 + 1][tx];
            float4 w2 = WL4[kq4 * 4 + 2][tx];
            float4 w3 = WL4[kq4 * 4 + 3][tx];
#pragma unroll
            for (int i = 0; i < RPT; ++i) {
                float4 xv = XL4[ty * RPT + i][kq4];
                acc[i].x += xv.x * w0.x + xv.y * w1.x + xv.z * w2.x + xv.w * w3.x;
                acc[i].y += xv.x * w0.y + xv.y * w1.y + xv.z * w2.y + xv.w * w3.y;
                acc[i].z += xv.x * w0.z + xv.y * w1.z + xv.z * w2.z + xv.w * w3.z;
                acc[i].w += xv.x * w0.w + xv.y * w1.w + xv.z * w2.w + xv.w * w3.w;
            }
        }
        __syncthreads();
    }
    float4 bv = make_float4(0.f, 0.f, 0.f, 0.f);
    if (bias) bv = *(const float4*)&bias[tx * 4];
#pragma unroll
    for (int i = 0; i < RPT; ++i) {
        int gr = rowBase + ty * RPT + i;
        if (gr < M) {
            float4 v = acc[i];
            v.x += bv.x; v.y += bv.y; v.z += bv.z; v.w += bv.w;
            if (applyRelu) {
                v.x = fmaxf(v.x, 0.f); v.y = fmaxf(v.y, 0.f);
                v.z = fmaxf(v.z, 0.f); v.w = fmaxf(v.w, 0.f);
            }
            *(float4*)&C[(size_t)gr * NC + tx * 4] = v;
        }
    }
}

// --- wave-per-node gather aggregation: out = relu(sum coef*h[src] + dis^2*h[n] + b)
template <int NC>
__global__ __launch_bounds__(256) void aggregate_kernel(const float* __restrict__ h,
                                                        const float* __restrict__ dis,
                                                        const int* __restrict__ rowstart,
                                                        const int* __restrict__ csr_src,
                                                        const float* __restrict__ csr_coef,
                                                        const float* __restrict__ bias,
                                                        float* __restrict__ out, int N) {
    constexpr int FP = NC / 64;  // floats per lane
    int wid = (blockIdx.x * blockDim.x + threadIdx.x) >> 6;
    int lane = threadIdx.x & 63;
    if (wid >= N) return;
    int n = wid;
    float d = dis[n];
    float d2 = d * d;
    float acc[FP];
    const float* hself = &h[(size_t)n * NC + lane * FP];
#pragma unroll
    for (int i = 0; i < FP; ++i) acc[i] = hself[i] * d2;

    int beg = rowstart[n], end = rowstart[n + 1];
    for (int e0 = beg; e0 < end; e0 += 64) {
        int idx = e0 + lane;
        int sv = 0;
        float cv = 0.f;
        if (idx < end) { sv = csr_src[idx]; cv = csr_coef[idx]; }
        int cntc = min(64, end - e0);
        int j = 0;
        for (; j + 4 <= cntc; j += 4) {
            int s0 = __shfl(sv, j + 0), s1 = __shfl(sv, j + 1);
            int s2 = __shfl(sv, j + 2), s3 = __shfl(sv, j + 3);
            float c0 = __shfl(cv, j + 0), c1 = __shfl(cv, j + 1);
            float c2 = __shfl(cv, j + 2), c3 = __shfl(cv, j + 3);
            const float* p0 = &h[(size_t)s0 * NC + lane * FP];
            const float* p1 = &h[(size_t)s1 * NC + lane * FP];
            const float* p2 = &h[(size_t)s2 * NC + lane * FP];
            const float* p3 = &h[(size_t)s3 * NC + lane * FP];
            float v0[FP], v1[FP], v2[FP], v3[FP];
#pragma unroll
            for (int i = 0; i < FP; ++i) { v0[i] = p0[i]; v1[i] = p1[i]; v2[i] = p2[i]; v3[i] = p3[i]; }
#pragma unroll
            for (int i = 0; i < FP; ++i)
                acc[i] += v0[i] * c0 + v1[i] * c1 + v2[i] * c2 + v3[i] * c3;
        }
        for (; j < cntc; ++j) {
            int s = __shfl(sv, j);
            float c = __shfl(cv, j);
            const float* hp = &h[(size_t)s * NC + lane * FP];
#pragma unroll
            for (int i = 0; i < FP; ++i) acc[i] += hp[i] * c;
        }
    }
#pragma unroll
    for (int i = 0; i < FP; ++i) {
        float v = acc[i] + bias[lane * FP + i];
        out[(size_t)n * NC + lane * FP + i] = fmaxf(v, 0.f);
    }
}

// --- segment-mean pool helpers (batch is sorted) ---
__global__ __launch_bounds__(128) void pool_kernel(const float* __restrict__ a1,
                                                   const int* __restrict__ batch,
                                                   float* __restrict__ gsum, int N) {
    int f = threadIdx.x;  // 0..127
    int n0 = blockIdx.x * 128;
    int nend = min(n0 + 128, N);
    float acc = 0.f;
    int gcur = batch[n0];
    for (int n = n0; n < nend; ++n) {
        int g = batch[n];
        if (g != gcur) {
            atomicAdd(&gsum[gcur * 128 + f], acc);
            acc = 0.f;
            gcur = g;
        }
        acc += a1[(size_t)n * 128 + f];
    }
    atomicAdd(&gsum[gcur * 128 + f], acc);
}

__global__ __launch_bounds__(256) void count_batch_kernel(const int* __restrict__ batch,
                                                          int* __restrict__ gcnt, int N) {
    __shared__ int lc[64];
    int t = threadIdx.x;
    if (t < 64) lc[t] = 0;
    __syncthreads();
    int n = blockIdx.x * blockDim.x + t;
    if (n < N) atomicAdd(&lc[batch[n]], 1);
    __syncthreads();
    if (t < 64 && lc[t] > 0) atomicAdd(&gcnt[t], lc[t]);
}

__global__ __launch_bounds__(128) void finalize_kernel(const float* __restrict__ gsum,
                                                       const int* __restrict__ gcnt,
                                                       const float* __restrict__ Wf2,
                                                       const float* __restrict__ bf2,
                                                       float* __restrict__ out) {
    __shared__ float red0[128], red1[128];
    int g = blockIdx.x, f = threadIdx.x;
    float cntf = (float)max(gcnt[g], 1);
    float ge = gsum[g * 128 + f] / cntf;
    out[g * 128 + f] = ge;
    red0[f] = ge * Wf2[f * 2 + 0];
    red1[f] = ge * Wf2[f * 2 + 1];
    __syncthreads();
    for (int off = 64; off > 0; off >>= 1) {
        if (f < off) { red0[f] += red0[f + off]; red1[f] += red1[f + off]; }
        __syncthreads();
    }
    if (f == 0) {
        out[8192 + 1 + g * 2 + 0] = red0[0] + bf2[0];
        out[8192 + 1 + g * 2 + 1] = red1[0] + bf2[1];
        if (g == 0) out[8192] = 0.f;
    }
}

extern "C" void kernel_launch(void* const* d_in, const int* in_sizes, int n_in,
                              void* d_out, int out_size, void* d_ws, size_t ws_size,
                              hipStream_t stream) {
    const float* x   = (const float*)d_in[0];
    const float* W1  = (const float*)d_in[1];
    const float* b1  = (const float*)d_in[2];
    const float* W2  = (const float*)d_in[3];
    const float* b2  = (const float*)d_in[4];
    const float* Wf1 = (const float*)d_in[5];
    const float* bf1 = (const float*)d_in[6];
    const float* Wf2 = (const float*)d_in[7];
    const float* bf2 = (const float*)d_in[8];
    const int* edge  = (const int*)d_in[9];
    const int* batch = (const int*)d_in[10];

    const int N = in_sizes[10];      // 100000
    const int E = in_sizes[9] / 2;   // 3200000
    const int* srcA = edge;
    const int* dstA = edge + E;
    float* out = (float*)d_out;

    // workspace carve-up
    char* p = (char*)d_ws;
    auto alloc = [&](size_t bytes) {
        char* r = p;
        p += (bytes + 255) & ~(size_t)255;
        return r;
    };
    int*   cnt      = (int*)alloc((size_t)N * 4);
    int*   wofs     = (int*)alloc((size_t)N * 4);
    float* gsum     = (float*)alloc(64 * 128 * 4);
    int*   gcnt     = (int*)alloc(64 * 4);
    size_t zbytes   = (size_t)(p - (char*)d_ws);     // zero all of the above
    float* dis      = (float*)alloc((size_t)N * 4);
    int*   rowstart = (int*)alloc((size_t)(N + 1) * 4);
    int*   part     = (int*)alloc(1024 * 4);
    int*   csr_src  = (int*)alloc((size_t)E * 4);
    float* csr_coef = (float*)alloc((size_t)E * 4);
    float* bufA     = (float*)alloc((size_t)N * 128 * 4);
    float* bufB     = (float*)alloc((size_t)N * 128 * 4);

    hipMemsetAsync(d_ws, 0, zbytes, stream);

    const int NB = (N + 1023) / 1024;
    count_kernel<<<(E + 255) / 256, 256, 0, stream>>>(dstA, cnt, E);
    dis_kernel<<<(N + 255) / 256, 256, 0, stream>>>(cnt, dis, N);
    scan_partial_kernel<<<NB, 256, 0, stream>>>(cnt, part, N);
    scan_parts_kernel<<<1, 1, 0, stream>>>(part, rowstart, NB, N);
    scan_final_kernel<<<NB, 256, 0, stream>>>(cnt, part, rowstart, N);
    fill_kernel<<<(E + 255) / 256, 256, 0, stream>>>(srcA, dstA, dis, rowstart, wofs,
                                                     csr_src, csr_coef, E);

    // layer 1: h = x@W1 ; h1 = relu(agg + dis^2*h + b1)
    gemm_kernel<128, 128><<<(N + 63) / 64, 256, 0, stream>>>(x, W1, nullptr, bufA, N, 0);
    aggregate_kernel<128><<<(N + 3) / 4, 256, 0, stream>>>(bufA, dis, rowstart, csr_src,
                                                           csr_coef, b1, bufB, N);
    // layer 2: g = h1@W2 ; h2 = relu(agg + dis^2*g + b2)
    gemm_kernel<128, 64><<<(N + 63) / 64, 256, 0, stream>>>(bufB, W2, nullptr, bufA, N, 0);
    aggregate_kernel<64><<<(N + 3) / 4, 256, 0, stream>>>(bufA, dis, rowstart, csr_src,
                                                          csr_coef, b2, bufB, N);
    // head: a1 = h2@Wf1 + bf1
    gemm_kernel<64, 128><<<(N + 63) / 64, 256, 0, stream>>>(bufB, Wf1, bf1, bufA, N, 0);

    // segment-mean pool + tiny head
    pool_kernel<<<(N + 127) / 128, 128, 0, stream>>>(bufA, batch, gsum, N);
    count_batch_kernel<<<(N + 255) / 256, 256, 0, stream>>>(batch, gcnt, N);
    finalize_kernel<<<64, 128, 0, stream>>>(gsum, gcnt, Wf2, bf2, out);
}

// Round 2
// 999.879 us; speedup vs baseline: 1.0574x; 1.0574x over previous
//
#include <hip/hip_runtime.h>

// ---------------------------------------------------------------------------
// GCN forward: deg/dis -> CSR build (src only) -> [GEMM -> aggregate(relu)] x2
//              -> GEMM+bias -> segment-mean pool -> tiny head
// All fp32. coef = dis[src]*dis[dst] computed on the fly in aggregate
// (dis is 400KB -> L2-resident), so CSR stores only src (4B/edge scatter).
// ---------------------------------------------------------------------------

__global__ __launch_bounds__(256) void count_kernel(const int* __restrict__ dst,
                                                    int* __restrict__ cnt, int E) {
    int e = blockIdx.x * blockDim.x + threadIdx.x;
    if (e < E) atomicAdd(&cnt[dst[e]], 1);
}

__global__ __launch_bounds__(256) void dis_kernel(const int* __restrict__ cnt,
                                                  float* __restrict__ dis, int N) {
    int n = blockIdx.x * blockDim.x + threadIdx.x;
    if (n < N) dis[n] = rsqrtf(1.0f + (float)cnt[n]);
}

__global__ __launch_bounds__(256) void scan_partial_kernel(const int* __restrict__ cnt,
                                                           int* __restrict__ part, int N) {
    __shared__ int sdata[256];
    int b = blockIdx.x, t = threadIdx.x;
    int base = b * 1024;
    int s = 0;
#pragma unroll
    for (int i = 0; i < 4; ++i) {
        int idx = base + t * 4 + i;
        if (idx < N) s += cnt[idx];
    }
    sdata[t] = s;
    __syncthreads();
    for (int off = 128; off > 0; off >>= 1) {
        if (t < off) sdata[t] += sdata[t + off];
        __syncthreads();
    }
    if (t == 0) part[b] = sdata[0];
}

__global__ void scan_parts_kernel(int* __restrict__ part, int* __restrict__ rowstart,
                                  int NB, int N) {
    if (blockIdx.x == 0 && threadIdx.x == 0) {
        int run = 0;
        for (int i = 0; i < NB; ++i) { int v = part[i]; part[i] = run; run += v; }
        rowstart[N] = run;
    }
}

__global__ __launch_bounds__(256) void scan_final_kernel(const int* __restrict__ cnt,
                                                         const int* __restrict__ part,
                                                         int* __restrict__ rowstart, int N) {
    __shared__ int sdata[256];
    int b = blockIdx.x, t = threadIdx.x;
    int base = b * 1024;
    int v[4];
    int s = 0;
#pragma unroll
    for (int i = 0; i < 4; ++i) {
        int idx = base + t * 4 + i;
        v[i] = (idx < N) ? cnt[idx] : 0;
        s += v[i];
    }
    sdata[t] = s;
    __syncthreads();
    for (int off = 1; off < 256; off <<= 1) {
        int tmp = 0;
        if (t >= off) tmp = sdata[t - off];
        __syncthreads();
        sdata[t] += tmp;
        __syncthreads();
    }
    int run = part[b] + sdata[t] - s;  // exclusive prefix for this thread
#pragma unroll
    for (int i = 0; i < 4; ++i) {
        int idx = base + t * 4 + i;
        if (idx < N) rowstart[idx] = run;
        run += v[i];
    }
}

// scatter only src index (4B/edge); coef recomputed at gather time
__global__ __launch_bounds__(256) void fill_kernel(const int* __restrict__ src,
                                                   const int* __restrict__ dst,
                                                   const int* __restrict__ rowstart,
                                                   int* __restrict__ wofs,
                                                   int* __restrict__ csr_src, int E) {
    int e = blockIdx.x * blockDim.x + threadIdx.x;
    if (e >= E) return;
    int d = dst[e], s = src[e];
    int p = rowstart[d] + atomicAdd(&wofs[d], 1);
    csr_src[p] = s;
}

// --- tiled fp32 GEMM: C[M][NC] = X[M][K] @ W[K][NC] (+bias) ---
template <int K, int NC>
__global__ __launch_bounds__(256) void gemm_kernel(const float* __restrict__ X,
                                                   const float* __restrict__ W,
                                                   const float* __restrict__ bias,
                                                   float* __restrict__ C, int M) {
    constexpr int CG = NC / 4;    // col groups of 4
    constexpr int RG = 256 / CG;  // row groups
    constexpr int RPT = 64 / RG;  // rows per thread
    __shared__ float4 XL4[64][9];       // 64 rows x 32 k-floats (pad to 36)
    __shared__ float4 WL4[32][CG];      // 32 k x NC cols
    int tid = threadIdx.x;
    int tx = tid % CG, ty = tid / CG;
    int rowBase = blockIdx.x * 64;
    float4 acc[RPT];
#pragma unroll
    for (int i = 0; i < RPT; ++i) acc[i] = make_float4(0.f, 0.f, 0.f, 0.f);

    for (int kk = 0; kk < K; kk += 32) {
#pragma unroll
        for (int q = 0; q < 2; ++q) {
            int li = q * 256 + tid;
            int r = li >> 3, c4 = li & 7;
            int gr = rowBase + r;
            if (gr >= M) gr = M - 1;
            XL4[r][c4] = *(const float4*)&X[(size_t)gr * K + kk + c4 * 4];
        }
        constexpr int WPT = (32 * CG) / 256;
#pragma unroll
        for (int q = 0; q < WPT; ++q) {
            int li = q * 256 + tid;
            int k = li / CG, c4 = li % CG;
            WL4[k][c4] = *(const float4*)&W[(size_t)(kk + k) * NC + c4 * 4];
        }
        __syncthreads();
#pragma unroll
        for (int kq4 = 0; kq4 < 8; ++kq4) {
            float4 w0 = WL4[kq4 * 4 + 0][tx];
            float4 w1 = WL4[kq4 * 4 + 1][tx];
            float4 w2 = WL4[kq4 * 4 + 2][tx];
            float4 w3 = WL4[kq4 * 4 + 3][tx];
#pragma unroll
            for (int i = 0; i < RPT; ++i) {
                float4 xv = XL4[ty * RPT + i][kq4];
                acc[i].x += xv.x * w0.x + xv.y * w1.x + xv.z * w2.x + xv.w * w3.x;
                acc[i].y += xv.x * w0.y + xv.y * w1.y + xv.z * w2.y + xv.w * w3.y;
                acc[i].z += xv.x * w0.z + xv.y * w1.z + xv.z * w2.z + xv.w * w3.z;
                acc[i].w += xv.x * w0.w + xv.y * w1.w + xv.z * w2.w + xv.w * w3.w;
            }
        }
        __syncthreads();
    }
    float4 bv = make_float4(0.f, 0.f, 0.f, 0.f);
    if (bias) bv = *(const float4*)&bias[tx * 4];
#pragma unroll
    for (int i = 0; i < RPT; ++i) {
        int gr = rowBase + ty * RPT + i;
        if (gr < M) {
            float4 v = acc[i];
            v.x += bv.x; v.y += bv.y; v.z += bv.z; v.w += bv.w;
            *(float4*)&C[(size_t)gr * NC + tx * 4] = v;
        }
    }
}

// --- wave-per-node gather aggregation, float4 sub-wave rows:
//     inner = sum_e dis[s_e]*h[s_e]  (+ d*h[n] once)
//     out   = relu(d*inner + bias)
template <int NC>
__global__ __launch_bounds__(256) void aggregate_kernel(const float* __restrict__ h,
                                                        const float* __restrict__ dis,
                                                        const int* __restrict__ rowstart,
                                                        const int* __restrict__ csr_src,
                                                        const float* __restrict__ bias,
                                                        float* __restrict__ out, int N) {
    constexpr int LPR = NC / 4;   // lanes per row (32 for NC=128, 16 for NC=64)
    constexpr int RPS = 64 / LPR; // rows (edges) per step (2 or 4)
    int wid = (blockIdx.x * blockDim.x + threadIdx.x) >> 6;
    int lane = threadIdx.x & 63;
    if (wid >= N) return;
    int n = wid;
    int sub = lane / LPR;
    int fid = lane % LPR;
    const float4* h4 = (const float4*)h;
    float d = dis[n];
    float4 acc = make_float4(0.f, 0.f, 0.f, 0.f);
    if (sub == 0) {
        float4 hv = h4[(size_t)n * LPR + fid];
        acc.x = hv.x * d; acc.y = hv.y * d; acc.z = hv.z * d; acc.w = hv.w * d;
    }

    int beg = rowstart[n], end = rowstart[n + 1];
    for (int e0 = beg; e0 < end; e0 += 64) {
        int idx = e0 + lane;
        int sv = 0;
        float dv = 0.f;
        if (idx < end) { sv = csr_src[idx]; dv = dis[sv]; }
        int cnt = min(64, end - e0);
        int j = 0;
        // main: 2*RPS edges per iteration (2 float4 loads in flight per lane)
        for (; j + 2 * RPS <= cnt; j += 2 * RPS) {
            int ja = j + sub, jb = j + RPS + sub;
            int sa = __shfl(sv, ja); float ca = __shfl(dv, ja);
            int sb = __shfl(sv, jb); float cb = __shfl(dv, jb);
            float4 va = h4[(size_t)sa * LPR + fid];
            float4 vb = h4[(size_t)sb * LPR + fid];
            acc.x += va.x * ca + vb.x * cb;
            acc.y += va.y * ca + vb.y * cb;
            acc.z += va.z * ca + vb.z * cb;
            acc.w += va.w * ca + vb.w * cb;
        }
        // tail: RPS edges per iteration, masked by coefficient
        for (; j < cnt; j += RPS) {
            int jj = j + sub;
            int jc = min(jj, cnt - 1);
            int s = __shfl(sv, jc);
            float c = __shfl(dv, jc);
            if (jj >= cnt) c = 0.f;
            float4 v = h4[(size_t)s * LPR + fid];
            acc.x += v.x * c; acc.y += v.y * c; acc.z += v.z * c; acc.w += v.w * c;
        }
    }
    // combine sub-wave partial sums
#pragma unroll
    for (int m = LPR; m < 64; m <<= 1) {
        acc.x += __shfl_xor(acc.x, m);
        acc.y += __shfl_xor(acc.y, m);
        acc.z += __shfl_xor(acc.z, m);
        acc.w += __shfl_xor(acc.w, m);
    }
    if (sub == 0) {
        const float4 bv = *(const float4*)&bias[fid * 4];
        float4 v;
        v.x = fmaxf(acc.x * d + bv.x, 0.f);
        v.y = fmaxf(acc.y * d + bv.y, 0.f);
        v.z = fmaxf(acc.z * d + bv.z, 0.f);
        v.w = fmaxf(acc.w * d + bv.w, 0.f);
        *(float4*)&out[(size_t)n * NC + fid * 4] = v;
    }
}

// --- segment-mean pool helpers (batch is sorted) ---
__global__ __launch_bounds__(128) void pool_kernel(const float* __restrict__ a1,
                                                   const int* __restrict__ batch,
                                                   float* __restrict__ gsum, int N) {
    int f = threadIdx.x;  // 0..127
    int n0 = blockIdx.x * 128;
    int nend = min(n0 + 128, N);
    float acc = 0.f;
    int gcur = batch[n0];
    for (int n = n0; n < nend; ++n) {
        int g = batch[n];
        if (g != gcur) {
            atomicAdd(&gsum[gcur * 128 + f], acc);
            acc = 0.f;
            gcur = g;
        }
        acc += a1[(size_t)n * 128 + f];
    }
    atomicAdd(&gsum[gcur * 128 + f], acc);
}

__global__ __launch_bounds__(256) void count_batch_kernel(const int* __restrict__ batch,
                                                          int* __restrict__ gcnt, int N) {
    __shared__ int lc[64];
    int t = threadIdx.x;
    if (t < 64) lc[t] = 0;
    __syncthreads();
    int n = blockIdx.x * blockDim.x + t;
    if (n < N) atomicAdd(&lc[batch[n]], 1);
    __syncthreads();
    if (t < 64 && lc[t] > 0) atomicAdd(&gcnt[t], lc[t]);
}

__global__ __launch_bounds__(128) void finalize_kernel(const float* __restrict__ gsum,
                                                       const int* __restrict__ gcnt,
                                                       const float* __restrict__ Wf2,
                                                       const float* __restrict__ bf2,
                                                       float* __restrict__ out) {
    __shared__ float red0[128], red1[128];
    int g = blockIdx.x, f = threadIdx.x;
    float cntf = (float)max(gcnt[g], 1);
    float ge = gsum[g * 128 + f] / cntf;
    out[g * 128 + f] = ge;
    red0[f] = ge * Wf2[f * 2 + 0];
    red1[f] = ge * Wf2[f * 2 + 1];
    __syncthreads();
    for (int off = 64; off > 0; off >>= 1) {
        if (f < off) { red0[f] += red0[f + off]; red1[f] += red1[f + off]; }
        __syncthreads();
    }
    if (f == 0) {
        out[8192 + 1 + g * 2 + 0] = red0[0] + bf2[0];
        out[8192 + 1 + g * 2 + 1] = red1[0] + bf2[1];
        if (g == 0) out[8192] = 0.f;
    }
}

extern "C" void kernel_launch(void* const* d_in, const int* in_sizes, int n_in,
                              void* d_out, int out_size, void* d_ws, size_t ws_size,
                              hipStream_t stream) {
    const float* x   = (const float*)d_in[0];
    const float* W1  = (const float*)d_in[1];
    const float* b1  = (const float*)d_in[2];
    const float* W2  = (const float*)d_in[3];
    const float* b2  = (const float*)d_in[4];
    const float* Wf1 = (const float*)d_in[5];
    const float* bf1 = (const float*)d_in[6];
    const float* Wf2 = (const float*)d_in[7];
    const float* bf2 = (const float*)d_in[8];
    const int* edge  = (const int*)d_in[9];
    const int* batch = (const int*)d_in[10];

    const int N = in_sizes[10];      // 100000
    const int E = in_sizes[9] / 2;   // 3200000
    const int* srcA = edge;
    const int* dstA = edge + E;
    float* out = (float*)d_out;

    // workspace carve-up
    char* p = (char*)d_ws;
    auto alloc = [&](size_t bytes) {
        char* r = p;
        p += (bytes + 255) & ~(size_t)255;
        return r;
    };
    int*   cnt      = (int*)alloc((size_t)N * 4);
    int*   wofs     = (int*)alloc((size_t)N * 4);
    float* gsum     = (float*)alloc(64 * 128 * 4);
    int*   gcnt     = (int*)alloc(64 * 4);
    size_t zbytes   = (size_t)(p - (char*)d_ws);     // zero all of the above
    float* dis      = (float*)alloc((size_t)N * 4);
    int*   rowstart = (int*)alloc((size_t)(N + 1) * 4);
    int*   part     = (int*)alloc(1024 * 4);
    int*   csr_src  = (int*)alloc((size_t)E * 4);
    float* bufA     = (float*)alloc((size_t)N * 128 * 4);
    float* bufB     = (float*)alloc((size_t)N * 128 * 4);

    hipMemsetAsync(d_ws, 0, zbytes, stream);

    const int NB = (N + 1023) / 1024;
    count_kernel<<<(E + 255) / 256, 256, 0, stream>>>(dstA, cnt, E);
    dis_kernel<<<(N + 255) / 256, 256, 0, stream>>>(cnt, dis, N);
    scan_partial_kernel<<<NB, 256, 0, stream>>>(cnt, part, N);
    scan_parts_kernel<<<1, 1, 0, stream>>>(part, rowstart, NB, N);
    scan_final_kernel<<<NB, 256, 0, stream>>>(cnt, part, rowstart, N);
    fill_kernel<<<(E + 255) / 256, 256, 0, stream>>>(srcA, dstA, rowstart, wofs,
                                                     csr_src, E);

    // layer 1: h = x@W1 ; h1 = relu(d*(sum dis_s*h_s + d*h_n) + b1)
    gemm_kernel<128, 128><<<(N + 63) / 64, 256, 0, stream>>>(x, W1, nullptr, bufA, N);
    aggregate_kernel<128><<<(N + 3) / 4, 256, 0, stream>>>(bufA, dis, rowstart, csr_src,
                                                           b1, bufB, N);
    // layer 2
    gemm_kernel<128, 64><<<(N + 63) / 64, 256, 0, stream>>>(bufB, W2, nullptr, bufA, N);
    aggregate_kernel<64><<<(N + 3) / 4, 256, 0, stream>>>(bufA, dis, rowstart, csr_src,
                                                          b2, bufB, N);
    // head: a1 = h2@Wf1 + bf1
    gemm_kernel<64, 128><<<(N + 63) / 64, 256, 0, stream>>>(bufB, Wf1, bf1, bufA, N);

    // segment-mean pool + tiny head
    pool_kernel<<<(N + 127) / 128, 128, 0, stream>>>(bufA, batch, gsum, N);
    count_batch_kernel<<<(N + 255) / 256, 256, 0, stream>>>(batch, gcnt, N);
    finalize_kernel<<<64, 128, 0, stream>>>(gsum, gcnt, Wf2, bf2, out);
}

// Round 3
// 848.547 us; speedup vs baseline: 1.2460x; 1.1783x over previous
//
#include <hip/hip_runtime.h>

// ---------------------------------------------------------------------------
// GCN forward, bf16 activations / fp32 weights+accum:
//   deg/dis -> CSR(src) -> GEMM1(f32->bf16) -> agg1(bf16) -> GEMM2(bf16->bf16)
//   -> agg2(bf16) -> GEMM3(bf16->f32,+bias) -> segment-mean pool -> head
// Gather traffic halves vs fp32 (dominant cost). Only activations are rounded;
// weights stay fp32, accumulation fp32, outputs are graph-means -> error ~e-5.
// ---------------------------------------------------------------------------

__device__ __forceinline__ float bf2f(unsigned int lo16) {
    unsigned int v = lo16 << 16;
    return __builtin_bit_cast(float, v);
}
__device__ __forceinline__ unsigned short f2bf(float f) {
    unsigned int u = __builtin_bit_cast(unsigned int, f);
    u = (u + 0x7FFFu + ((u >> 16) & 1u)) >> 16;
    return (unsigned short)u;
}
__device__ __forceinline__ void cvt8(const uint4& v, float* f) {
    f[0] = bf2f(v.x & 0xFFFFu); f[1] = bf2f(v.x >> 16);
    f[2] = bf2f(v.y & 0xFFFFu); f[3] = bf2f(v.y >> 16);
    f[4] = bf2f(v.z & 0xFFFFu); f[5] = bf2f(v.z >> 16);
    f[6] = bf2f(v.w & 0xFFFFu); f[7] = bf2f(v.w >> 16);
}

__global__ __launch_bounds__(256) void count_kernel(const int* __restrict__ dst,
                                                    int* __restrict__ cnt, int E) {
    int e = blockIdx.x * blockDim.x + threadIdx.x;
    if (e < E) atomicAdd(&cnt[dst[e]], 1);
}

__global__ __launch_bounds__(256) void dis_kernel(const int* __restrict__ cnt,
                                                  float* __restrict__ dis, int N) {
    int n = blockIdx.x * blockDim.x + threadIdx.x;
    if (n < N) dis[n] = rsqrtf(1.0f + (float)cnt[n]);
}

__global__ __launch_bounds__(256) void scan_partial_kernel(const int* __restrict__ cnt,
                                                           int* __restrict__ part, int N) {
    __shared__ int sdata[256];
    int b = blockIdx.x, t = threadIdx.x;
    int base = b * 1024;
    int s = 0;
#pragma unroll
    for (int i = 0; i < 4; ++i) {
        int idx = base + t * 4 + i;
        if (idx < N) s += cnt[idx];
    }
    sdata[t] = s;
    __syncthreads();
    for (int off = 128; off > 0; off >>= 1) {
        if (t < off) sdata[t] += sdata[t + off];
        __syncthreads();
    }
    if (t == 0) part[b] = sdata[0];
}

__global__ void scan_parts_kernel(int* __restrict__ part, int* __restrict__ rowstart,
                                  int NB, int N) {
    if (blockIdx.x == 0 && threadIdx.x == 0) {
        int run = 0;
        for (int i = 0; i < NB; ++i) { int v = part[i]; part[i] = run; run += v; }
        rowstart[N] = run;
    }
}

__global__ __launch_bounds__(256) void scan_final_kernel(const int* __restrict__ cnt,
                                                         const int* __restrict__ part,
                                                         int* __restrict__ rowstart, int N) {
    __shared__ int sdata[256];
    int b = blockIdx.x, t = threadIdx.x;
    int base = b * 1024;
    int v[4];
    int s = 0;
#pragma unroll
    for (int i = 0; i < 4; ++i) {
        int idx = base + t * 4 + i;
        v[i] = (idx < N) ? cnt[idx] : 0;
        s += v[i];
    }
    sdata[t] = s;
    __syncthreads();
    for (int off = 1; off < 256; off <<= 1) {
        int tmp = 0;
        if (t >= off) tmp = sdata[t - off];
        __syncthreads();
        sdata[t] += tmp;
        __syncthreads();
    }
    int run = part[b] + sdata[t] - s;
#pragma unroll
    for (int i = 0; i < 4; ++i) {
        int idx = base + t * 4 + i;
        if (idx < N) rowstart[idx] = run;
        run += v[i];
    }
}

__global__ __launch_bounds__(256) void fill_kernel(const int* __restrict__ src,
                                                   const int* __restrict__ dst,
                                                   const int* __restrict__ rowstart,
                                                   int* __restrict__ wofs,
                                                   int* __restrict__ csr_src, int E) {
    int e = blockIdx.x * blockDim.x + threadIdx.x;
    if (e >= E) return;
    int d = dst[e], s = src[e];
    int p = rowstart[d] + atomicAdd(&wofs[d], 1);
    csr_src[p] = s;
}

// --- tiled GEMM: C[M][NC] = X[M][K] @ W[K][NC] (+bias). fp32 math in LDS/regs;
//     X may be bf16 (converted during staging), C may be written bf16.
template <int K, int NC, bool IN_BF16, bool OUT_BF16>
__global__ __launch_bounds__(256) void gemm_kernel(const void* __restrict__ Xv,
                                                   const float* __restrict__ W,
                                                   const float* __restrict__ bias,
                                                   void* __restrict__ Cv, int M) {
    constexpr int CG = NC / 4;    // col groups of 4
    constexpr int RG = 256 / CG;  // row groups
    constexpr int RPT = 64 / RG;  // rows per thread
    __shared__ float4 XL4[64][9];   // 64 rows x 32 k-floats (pad 8->9)
    __shared__ float4 WL4[32][CG];  // 32 k x NC cols
    int tid = threadIdx.x;
    int tx = tid % CG, ty = tid / CG;
    int rowBase = blockIdx.x * 64;
    float4 acc[RPT];
#pragma unroll
    for (int i = 0; i < RPT; ++i) acc[i] = make_float4(0.f, 0.f, 0.f, 0.f);

    for (int kk = 0; kk < K; kk += 32) {
        if (IN_BF16) {
            // one uint4 (8 bf16) per thread: 64 rows x 4 chunks = 256
            int r = tid >> 2, c8 = tid & 3;
            int gr = rowBase + r;
            if (gr >= M) gr = M - 1;
            const unsigned short* Xb = (const unsigned short*)Xv;
            uint4 v = *(const uint4*)&Xb[(size_t)gr * K + kk + c8 * 8];
            float f[8];
            cvt8(v, f);
            XL4[r][c8 * 2 + 0] = make_float4(f[0], f[1], f[2], f[3]);
            XL4[r][c8 * 2 + 1] = make_float4(f[4], f[5], f[6], f[7]);
        } else {
            const float* Xf = (const float*)Xv;
#pragma unroll
            for (int q = 0; q < 2; ++q) {
                int li = q * 256 + tid;
                int r = li >> 3, c4 = li & 7;
                int gr = rowBase + r;
                if (gr >= M) gr = M - 1;
                XL4[r][c4] = *(const float4*)&Xf[(size_t)gr * K + kk + c4 * 4];
            }
        }
        constexpr int WPT = (32 * CG) / 256;
#pragma unroll
        for (int q = 0; q < WPT; ++q) {
            int li = q * 256 + tid;
            int k = li / CG, c4 = li % CG;
            WL4[k][c4] = *(const float4*)&W[(size_t)(kk + k) * NC + c4 * 4];
        }
        __syncthreads();
#pragma unroll
        for (int kq4 = 0; kq4 < 8; ++kq4) {
            float4 w0 = WL4[kq4 * 4 + 0][tx];
            float4 w1 = WL4[kq4 * 4 + 1][tx];
            float4 w2 = WL4[kq4 * 4 + 2][tx];
            float4 w3 = WL4[kq4 * 4 + 3][tx];
#pragma unroll
            for (int i = 0; i < RPT; ++i) {
                float4 xv = XL4[ty * RPT + i][kq4];
                acc[i].x += xv.x * w0.x + xv.y * w1.x + xv.z * w2.x + xv.w * w3.x;
                acc[i].y += xv.x * w0.y + xv.y * w1.y + xv.z * w2.y + xv.w * w3.y;
                acc[i].z += xv.x * w0.z + xv.y * w1.z + xv.z * w2.z + xv.w * w3.z;
                acc[i].w += xv.x * w0.w + xv.y * w1.w + xv.z * w2.w + xv.w * w3.w;
            }
        }
        __syncthreads();
    }
    float4 bv = make_float4(0.f, 0.f, 0.f, 0.f);
    if (bias) bv = *(const float4*)&bias[tx * 4];
#pragma unroll
    for (int i = 0; i < RPT; ++i) {
        int gr = rowBase + ty * RPT + i;
        if (gr < M) {
            float4 v = acc[i];
            v.x += bv.x; v.y += bv.y; v.z += bv.z; v.w += bv.w;
            if (OUT_BF16) {
                unsigned short* Cb = (unsigned short*)Cv;
                ushort4 o;
                o.x = f2bf(v.x); o.y = f2bf(v.y); o.z = f2bf(v.z); o.w = f2bf(v.w);
                *(ushort4*)&Cb[(size_t)gr * NC + tx * 4] = o;
            } else {
                float* Cf = (float*)Cv;
                *(float4*)&Cf[(size_t)gr * NC + tx * 4] = v;
            }
        }
    }
}

// --- wave-per-node bf16 gather aggregation (fp32 accum):
//     out = relu(d * (sum_e dis[s]*h[s] + d*h[n]) + bias), bf16 out
template <int NC>
__global__ __launch_bounds__(256) void aggregate_kernel(const unsigned short* __restrict__ h,
                                                        const float* __restrict__ dis,
                                                        const int* __restrict__ rowstart,
                                                        const int* __restrict__ csr_src,
                                                        const float* __restrict__ bias,
                                                        unsigned short* __restrict__ out,
                                                        int N) {
    constexpr int LPR = NC / 8;   // lanes per row (16B = 8 bf16 each)
    constexpr int RPS = 64 / LPR; // rows (edges) per step (4 for 128, 8 for 64)
    int wid = (blockIdx.x * blockDim.x + threadIdx.x) >> 6;
    int lane = threadIdx.x & 63;
    if (wid >= N) return;
    int n = wid;
    int sub = lane / LPR;
    int fid = lane % LPR;
    const uint4* h4 = (const uint4*)h;  // row = LPR uint4
    float d = dis[n];
    float acc[8];
#pragma unroll
    for (int i = 0; i < 8; ++i) acc[i] = 0.f;
    if (sub == 0) {
        uint4 hv = h4[(size_t)n * LPR + fid];
        float f[8];
        cvt8(hv, f);
#pragma unroll
        for (int i = 0; i < 8; ++i) acc[i] = f[i] * d;
    }

    int beg = rowstart[n], end = rowstart[n + 1];
    for (int e0 = beg; e0 < end; e0 += 64) {
        int idx = e0 + lane;
        int sv = 0;
        float dv = 0.f;
        if (idx < end) { sv = csr_src[idx]; dv = dis[sv]; }
        int cnt = min(64, end - e0);
        int j = 0;
        for (; j + 2 * RPS <= cnt; j += 2 * RPS) {
            int ja = j + sub, jb = j + RPS + sub;
            int sa = __shfl(sv, ja); float ca = __shfl(dv, ja);
            int sb = __shfl(sv, jb); float cb = __shfl(dv, jb);
            uint4 va = h4[(size_t)sa * LPR + fid];
            uint4 vb = h4[(size_t)sb * LPR + fid];
            float fa[8], fb[8];
            cvt8(va, fa);
            cvt8(vb, fb);
#pragma unroll
            for (int i = 0; i < 8; ++i) acc[i] += fa[i] * ca + fb[i] * cb;
        }
        for (; j < cnt; j += RPS) {
            int jj = j + sub;
            int jc = min(jj, cnt - 1);
            int s = __shfl(sv, jc);
            float c = __shfl(dv, jc);
            if (jj >= cnt) c = 0.f;
            uint4 v = h4[(size_t)s * LPR + fid];
            float f[8];
            cvt8(v, f);
#pragma unroll
            for (int i = 0; i < 8; ++i) acc[i] += f[i] * c;
        }
    }
#pragma unroll
    for (int m = LPR; m < 64; m <<= 1) {
#pragma unroll
        for (int i = 0; i < 8; ++i) acc[i] += __shfl_xor(acc[i], m);
    }
    if (sub == 0) {
        const float4 bv0 = *(const float4*)&bias[fid * 8 + 0];
        const float4 bv1 = *(const float4*)&bias[fid * 8 + 4];
        float r[8];
        r[0] = fmaxf(acc[0] * d + bv0.x, 0.f);
        r[1] = fmaxf(acc[1] * d + bv0.y, 0.f);
        r[2] = fmaxf(acc[2] * d + bv0.z, 0.f);
        r[3] = fmaxf(acc[3] * d + bv0.w, 0.f);
        r[4] = fmaxf(acc[4] * d + bv1.x, 0.f);
        r[5] = fmaxf(acc[5] * d + bv1.y, 0.f);
        r[6] = fmaxf(acc[6] * d + bv1.z, 0.f);
        r[7] = fmaxf(acc[7] * d + bv1.w, 0.f);
        uint4 o;
        o.x = (unsigned)f2bf(r[0]) | ((unsigned)f2bf(r[1]) << 16);
        o.y = (unsigned)f2bf(r[2]) | ((unsigned)f2bf(r[3]) << 16);
        o.z = (unsigned)f2bf(r[4]) | ((unsigned)f2bf(r[5]) << 16);
        o.w = (unsigned)f2bf(r[6]) | ((unsigned)f2bf(r[7]) << 16);
        *(uint4*)&out[(size_t)n * NC + fid * 8] = o;
    }
}

// --- segment-mean pool helpers (batch is sorted) ---
__global__ __launch_bounds__(128) void pool_kernel(const float* __restrict__ a1,
                                                   const int* __restrict__ batch,
                                                   float* __restrict__ gsum, int N) {
    int f = threadIdx.x;
    int n0 = blockIdx.x * 128;
    int nend = min(n0 + 128, N);
    float acc = 0.f;
    int gcur = batch[n0];
    for (int n = n0; n < nend; ++n) {
        int g = batch[n];
        if (g != gcur) {
            atomicAdd(&gsum[gcur * 128 + f], acc);
            acc = 0.f;
            gcur = g;
        }
        acc += a1[(size_t)n * 128 + f];
    }
    atomicAdd(&gsum[gcur * 128 + f], acc);
}

__global__ __launch_bounds__(256) void count_batch_kernel(const int* __restrict__ batch,
                                                          int* __restrict__ gcnt, int N) {
    __shared__ int lc[64];
    int t = threadIdx.x;
    if (t < 64) lc[t] = 0;
    __syncthreads();
    int n = blockIdx.x * blockDim.x + t;
    if (n < N) atomicAdd(&lc[batch[n]], 1);
    __syncthreads();
    if (t < 64 && lc[t] > 0) atomicAdd(&gcnt[t], lc[t]);
}

__global__ __launch_bounds__(128) void finalize_kernel(const float* __restrict__ gsum,
                                                       const int* __restrict__ gcnt,
                                                       const float* __restrict__ Wf2,
                                                       const float* __restrict__ bf2,
                                                       float* __restrict__ out) {
    __shared__ float red0[128], red1[128];
    int g = blockIdx.x, f = threadIdx.x;
    float cntf = (float)max(gcnt[g], 1);
    float ge = gsum[g * 128 + f] / cntf;
    out[g * 128 + f] = ge;
    red0[f] = ge * Wf2[f * 2 + 0];
    red1[f] = ge * Wf2[f * 2 + 1];
    __syncthreads();
    for (int off = 64; off > 0; off >>= 1) {
        if (f < off) { red0[f] += red0[f + off]; red1[f] += red1[f + off]; }
        __syncthreads();
    }
    if (f == 0) {
        out[8192 + 1 + g * 2 + 0] = red0[0] + bf2[0];
        out[8192 + 1 + g * 2 + 1] = red1[0] + bf2[1];
        if (g == 0) out[8192] = 0.f;
    }
}

extern "C" void kernel_launch(void* const* d_in, const int* in_sizes, int n_in,
                              void* d_out, int out_size, void* d_ws, size_t ws_size,
                              hipStream_t stream) {
    const float* x   = (const float*)d_in[0];
    const float* W1  = (const float*)d_in[1];
    const float* b1  = (const float*)d_in[2];
    const float* W2  = (const float*)d_in[3];
    const float* b2  = (const float*)d_in[4];
    const float* Wf1 = (const float*)d_in[5];
    const float* bf1 = (const float*)d_in[6];
    const float* Wf2 = (const float*)d_in[7];
    const float* bf2 = (const float*)d_in[8];
    const int* edge  = (const int*)d_in[9];
    const int* batch = (const int*)d_in[10];

    const int N = in_sizes[10];      // 100000
    const int E = in_sizes[9] / 2;   // 3200000
    const int* srcA = edge;
    const int* dstA = edge + E;
    float* out = (float*)d_out;

    char* p = (char*)d_ws;
    auto alloc = [&](size_t bytes) {
        char* r = p;
        p += (bytes + 255) & ~(size_t)255;
        return r;
    };
    int*   cnt      = (int*)alloc((size_t)N * 4);
    int*   wofs     = (int*)alloc((size_t)N * 4);
    float* gsum     = (float*)alloc(64 * 128 * 4);
    int*   gcnt     = (int*)alloc(64 * 4);
    size_t zbytes   = (size_t)(p - (char*)d_ws);
    float* dis      = (float*)alloc((size_t)N * 4);
    int*   rowstart = (int*)alloc((size_t)(N + 1) * 4);
    int*   part     = (int*)alloc(1024 * 4);
    int*   csr_src  = (int*)alloc((size_t)E * 4);
    float* bufA     = (float*)alloc((size_t)N * 128 * 4);  // h/g (bf16) then a1 (f32)
    float* bufB     = (float*)alloc((size_t)N * 128 * 2);  // h1/h2 (bf16)

    unsigned short* bufAb = (unsigned short*)bufA;
    unsigned short* bufBb = (unsigned short*)bufB;

    hipMemsetAsync(d_ws, 0, zbytes, stream);

    const int NB = (N + 1023) / 1024;
    count_kernel<<<(E + 255) / 256, 256, 0, stream>>>(dstA, cnt, E);
    dis_kernel<<<(N + 255) / 256, 256, 0, stream>>>(cnt, dis, N);
    scan_partial_kernel<<<NB, 256, 0, stream>>>(cnt, part, N);
    scan_parts_kernel<<<1, 1, 0, stream>>>(part, rowstart, NB, N);
    scan_final_kernel<<<NB, 256, 0, stream>>>(cnt, part, rowstart, N);
    fill_kernel<<<(E + 255) / 256, 256, 0, stream>>>(srcA, dstA, rowstart, wofs,
                                                     csr_src, E);

    // layer 1: h = x@W1 (bf16) ; h1 = relu(d*(sum dis_s*h_s + d*h_n) + b1) (bf16)
    gemm_kernel<128, 128, false, true><<<(N + 63) / 64, 256, 0, stream>>>(x, W1, nullptr,
                                                                          bufAb, N);
    aggregate_kernel<128><<<(N + 3) / 4, 256, 0, stream>>>(bufAb, dis, rowstart, csr_src,
                                                           b1, bufBb, N);
    // layer 2: g = h1@W2 (bf16) ; h2 = relu(...) (bf16)
    gemm_kernel<128, 64, true, true><<<(N + 63) / 64, 256, 0, stream>>>(bufBb, W2, nullptr,
                                                                        bufAb, N);
    aggregate_kernel<64><<<(N + 3) / 4, 256, 0, stream>>>(bufAb, dis, rowstart, csr_src,
                                                          b2, bufBb, N);
    // head: a1 = h2@Wf1 + bf1 (fp32)
    gemm_kernel<64, 128, true, false><<<(N + 63) / 64, 256, 0, stream>>>(bufBb, Wf1, bf1,
                                                                         bufA, N);

    pool_kernel<<<(N + 127) / 128, 128, 0, stream>>>(bufA, batch, gsum, N);
    count_batch_kernel<<<(N + 255) / 256, 256, 0, stream>>>(batch, gcnt, N);
    finalize_kernel<<<64, 128, 0, stream>>>(gsum, gcnt, Wf2, bf2, out);
}

// Round 4
// 657.916 us; speedup vs baseline: 1.6070x; 1.2898x over previous
//
#include <hip/hip_runtime.h>

// ---------------------------------------------------------------------------
// GCN forward, bf16 activations / fp32 weights+accum.
// CSR build via bucketed radix (bucket = dst>>9, 512 nodes/bucket):
//   A1 hist -> scan(bstart) -> A2 stage packed(src|ldst<<17) into bucket window
//   -> B per-bucket: per-node count/scan (writes rowstart+dis) + place csr_src.
// Then GEMM1 -> agg1 -> GEMM2 -> agg2 -> GEMM3 -> pool -> head.
// ---------------------------------------------------------------------------

__device__ __forceinline__ float bf2f(unsigned int lo16) {
    unsigned int v = lo16 << 16;
    return __builtin_bit_cast(float, v);
}
__device__ __forceinline__ unsigned short f2bf(float f) {
    unsigned int u = __builtin_bit_cast(unsigned int, f);
    u = (u + 0x7FFFu + ((u >> 16) & 1u)) >> 16;
    return (unsigned short)u;
}
__device__ __forceinline__ void cvt8(const uint4& v, float* f) {
    f[0] = bf2f(v.x & 0xFFFFu); f[1] = bf2f(v.x >> 16);
    f[2] = bf2f(v.y & 0xFFFFu); f[3] = bf2f(v.y >> 16);
    f[4] = bf2f(v.z & 0xFFFFu); f[5] = bf2f(v.z >> 16);
    f[6] = bf2f(v.w & 0xFFFFu); f[7] = bf2f(v.w >> 16);
}

// --- A1: bucket histogram (bucket = dst >> 9) ---
__global__ __launch_bounds__(256) void bucket_hist_kernel(const int* __restrict__ dst,
                                                          int* __restrict__ bcount, int E) {
    __shared__ int h[256];
    int t = threadIdx.x;
    h[t] = 0;
    __syncthreads();
    int base = blockIdx.x * 4096;
#pragma unroll
    for (int i = 0; i < 16; ++i) {
        int e = base + t + i * 256;
        if (e < E) atomicAdd(&h[dst[e] >> 9], 1);
    }
    __syncthreads();
    if (h[t] > 0) atomicAdd(&bcount[t], h[t]);
}

// --- scan over bucket counts -> bstart (exclusive), plus rowstart[N]=E ---
__global__ void bucket_scan_kernel(const int* __restrict__ bcount, int* __restrict__ bstart,
                                   int* __restrict__ rowstart, int NB, int N, int E) {
    __shared__ int s[256];
    int t = threadIdx.x;
    int v = (t < NB) ? bcount[t] : 0;
    s[t] = v;
    __syncthreads();
    for (int off = 1; off < 256; off <<= 1) {
        int tmp = 0;
        if (t >= off) tmp = s[t - off];
        __syncthreads();
        s[t] += tmp;
        __syncthreads();
    }
    bstart[t] = s[t] - v;            // exclusive prefix
    if (t == 255) bstart[256] = s[255];  // == E for all idx >= NB
    if (t == 0) rowstart[N] = E;
}

// --- A2: stage packed (src | local_dst<<17) into bucket windows ---
__global__ __launch_bounds__(256) void bucket_scatter_kernel(const int* __restrict__ src,
                                                             const int* __restrict__ dst,
                                                             const int* __restrict__ bstart,
                                                             int* __restrict__ bfill,
                                                             unsigned int* __restrict__ stage,
                                                             int E) {
    __shared__ int hist[256];
    __shared__ int abase[256];
    int t = threadIdx.x;
    hist[t] = 0;
    __syncthreads();
    int base = blockIdx.x * 4096;
#pragma unroll
    for (int i = 0; i < 16; ++i) {
        int e = base + t + i * 256;
        if (e < E) atomicAdd(&hist[dst[e] >> 9], 1);
    }
    __syncthreads();
    if (hist[t] > 0) {
        int r = atomicAdd(&bfill[t], hist[t]);
        abase[t] = bstart[t] + r;
    }
    __syncthreads();
    hist[t] = 0;
    __syncthreads();
#pragma unroll
    for (int i = 0; i < 16; ++i) {
        int e = base + t + i * 256;
        if (e < E) {
            int d = dst[e];
            int b = d >> 9;
            int slot = atomicAdd(&hist[b], 1);
            stage[abase[b] + slot] = (unsigned)src[e] | ((unsigned)(d & 511) << 17);
        }
    }
}

// --- B: per-bucket CSR finalize: per-node counts -> rowstart+dis, place src ---
__global__ __launch_bounds__(256) void csr_build_kernel(const unsigned int* __restrict__ stage,
                                                        const int* __restrict__ bstart,
                                                        int* __restrict__ rowstart,
                                                        float* __restrict__ dis,
                                                        int* __restrict__ csr_src, int N) {
    __shared__ int cnt[512];
    __shared__ int ofs[512];
    __shared__ int psum[256];
    int b = blockIdx.x, t = threadIdx.x;
    int node0 = b << 9;
    int nb = min(512, N - node0);
    cnt[t] = 0;
    cnt[t + 256] = 0;
    __syncthreads();
    int eb = bstart[b], ee = bstart[b + 1];
    for (int e = eb + t; e < ee; e += 256) {
        unsigned w = stage[e];
        atomicAdd(&cnt[w >> 17], 1);
    }
    __syncthreads();
    int a = cnt[2 * t], c = cnt[2 * t + 1];
    int ps = a + c;
    psum[t] = ps;
    __syncthreads();
    for (int off = 1; off < 256; off <<= 1) {
        int tmp = 0;
        if (t >= off) tmp = psum[t - off];
        __syncthreads();
        psum[t] += tmp;
        __syncthreads();
    }
    int ex = psum[t] - ps;
    ofs[2 * t] = ex;
    ofs[2 * t + 1] = ex + a;
    if (2 * t < nb) {
        rowstart[node0 + 2 * t] = eb + ex;
        dis[node0 + 2 * t] = rsqrtf(1.f + (float)a);
    }
    if (2 * t + 1 < nb) {
        rowstart[node0 + 2 * t + 1] = eb + ex + a;
        dis[node0 + 2 * t + 1] = rsqrtf(1.f + (float)c);
    }
    __syncthreads();
    for (int e = eb + t; e < ee; e += 256) {
        unsigned w = stage[e];
        int l = w >> 17;
        int slot = atomicAdd(&ofs[l], 1);
        csr_src[eb + slot] = (int)(w & 0x1FFFFu);
    }
}

// --- tiled GEMM: C[M][NC] = X[M][K] @ W[K][NC] (+bias). fp32 math in LDS/regs;
//     X may be bf16 (converted during staging), C may be written bf16.
template <int K, int NC, bool IN_BF16, bool OUT_BF16>
__global__ __launch_bounds__(256) void gemm_kernel(const void* __restrict__ Xv,
                                                   const float* __restrict__ W,
                                                   const float* __restrict__ bias,
                                                   void* __restrict__ Cv, int M) {
    constexpr int CG = NC / 4;    // col groups of 4
    constexpr int RG = 256 / CG;  // row groups
    constexpr int RPT = 64 / RG;  // rows per thread
    __shared__ float4 XL4[64][9];   // 64 rows x 32 k-floats (pad 8->9)
    __shared__ float4 WL4[32][CG];  // 32 k x NC cols
    int tid = threadIdx.x;
    int tx = tid % CG, ty = tid / CG;
    int rowBase = blockIdx.x * 64;
    float4 acc[RPT];
#pragma unroll
    for (int i = 0; i < RPT; ++i) acc[i] = make_float4(0.f, 0.f, 0.f, 0.f);

    for (int kk = 0; kk < K; kk += 32) {
        if (IN_BF16) {
            int r = tid >> 2, c8 = tid & 3;
            int gr = rowBase + r;
            if (gr >= M) gr = M - 1;
            const unsigned short* Xb = (const unsigned short*)Xv;
            uint4 v = *(const uint4*)&Xb[(size_t)gr * K + kk + c8 * 8];
            float f[8];
            cvt8(v, f);
            XL4[r][c8 * 2 + 0] = make_float4(f[0], f[1], f[2], f[3]);
            XL4[r][c8 * 2 + 1] = make_float4(f[4], f[5], f[6], f[7]);
        } else {
            const float* Xf = (const float*)Xv;
#pragma unroll
            for (int q = 0; q < 2; ++q) {
                int li = q * 256 + tid;
                int r = li >> 3, c4 = li & 7;
                int gr = rowBase + r;
                if (gr >= M) gr = M - 1;
                XL4[r][c4] = *(const float4*)&Xf[(size_t)gr * K + kk + c4 * 4];
            }
        }
        constexpr int WPT = (32 * CG) / 256;
#pragma unroll
        for (int q = 0; q < WPT; ++q) {
            int li = q * 256 + tid;
            int k = li / CG, c4 = li % CG;
            WL4[k][c4] = *(const float4*)&W[(size_t)(kk + k) * NC + c4 * 4];
        }
        __syncthreads();
#pragma unroll
        for (int kq4 = 0; kq4 < 8; ++kq4) {
            float4 w0 = WL4[kq4 * 4 + 0][tx];
            float4 w1 = WL4[kq4 * 4 + 1][tx];
            float4 w2 = WL4[kq4 * 4 + 2][tx];
            float4 w3 = WL4[kq4 * 4 + 3][tx];
#pragma unroll
            for (int i = 0; i < RPT; ++i) {
                float4 xv = XL4[ty * RPT + i][kq4];
                acc[i].x += xv.x * w0.x + xv.y * w1.x + xv.z * w2.x + xv.w * w3.x;
                acc[i].y += xv.x * w0.y + xv.y * w1.y + xv.z * w2.y + xv.w * w3.y;
                acc[i].z += xv.x * w0.z + xv.y * w1.z + xv.z * w2.z + xv.w * w3.z;
                acc[i].w += xv.x * w0.w + xv.y * w1.w + xv.z * w2.w + xv.w * w3.w;
            }
        }
        __syncthreads();
    }
    float4 bv = make_float4(0.f, 0.f, 0.f, 0.f);
    if (bias) bv = *(const float4*)&bias[tx * 4];
#pragma unroll
    for (int i = 0; i < RPT; ++i) {
        int gr = rowBase + ty * RPT + i;
        if (gr < M) {
            float4 v = acc[i];
            v.x += bv.x; v.y += bv.y; v.z += bv.z; v.w += bv.w;
            if (OUT_BF16) {
                unsigned short* Cb = (unsigned short*)Cv;
                ushort4 o;
                o.x = f2bf(v.x); o.y = f2bf(v.y); o.z = f2bf(v.z); o.w = f2bf(v.w);
                *(ushort4*)&Cb[(size_t)gr * NC + tx * 4] = o;
            } else {
                float* Cf = (float*)Cv;
                *(float4*)&Cf[(size_t)gr * NC + tx * 4] = v;
            }
        }
    }
}

// --- wave-per-node bf16 gather aggregation (fp32 accum) ---
template <int NC>
__global__ __launch_bounds__(256) void aggregate_kernel(const unsigned short* __restrict__ h,
                                                        const float* __restrict__ dis,
                                                        const int* __restrict__ rowstart,
                                                        const int* __restrict__ csr_src,
                                                        const float* __restrict__ bias,
                                                        unsigned short* __restrict__ out,
                                                        int N) {
    constexpr int LPR = NC / 8;   // lanes per row (16B = 8 bf16 each)
    constexpr int RPS = 64 / LPR; // rows (edges) per step
    int wid = (blockIdx.x * blockDim.x + threadIdx.x) >> 6;
    int lane = threadIdx.x & 63;
    if (wid >= N) return;
    int n = wid;
    int sub = lane / LPR;
    int fid = lane % LPR;
    const uint4* h4 = (const uint4*)h;
    float d = dis[n];
    float acc[8];
#pragma unroll
    for (int i = 0; i < 8; ++i) acc[i] = 0.f;
    if (sub == 0) {
        uint4 hv = h4[(size_t)n * LPR + fid];
        float f[8];
        cvt8(hv, f);
#pragma unroll
        for (int i = 0; i < 8; ++i) acc[i] = f[i] * d;
    }

    int beg = rowstart[n], end = rowstart[n + 1];
    for (int e0 = beg; e0 < end; e0 += 64) {
        int idx = e0 + lane;
        int sv = 0;
        float dv = 0.f;
        if (idx < end) { sv = csr_src[idx]; dv = dis[sv]; }
        int cnt = min(64, end - e0);
        int j = 0;
        for (; j + 2 * RPS <= cnt; j += 2 * RPS) {
            int ja = j + sub, jb = j + RPS + sub;
            int sa = __shfl(sv, ja); float ca = __shfl(dv, ja);
            int sb = __shfl(sv, jb); float cb = __shfl(dv, jb);
            uint4 va = h4[(size_t)sa * LPR + fid];
            uint4 vb = h4[(size_t)sb * LPR + fid];
            float fa[8], fb[8];
            cvt8(va, fa);
            cvt8(vb, fb);
#pragma unroll
            for (int i = 0; i < 8; ++i) acc[i] += fa[i] * ca + fb[i] * cb;
        }
        for (; j < cnt; j += RPS) {
            int jj = j + sub;
            int jc = min(jj, cnt - 1);
            int s = __shfl(sv, jc);
            float c = __shfl(dv, jc);
            if (jj >= cnt) c = 0.f;
            uint4 v = h4[(size_t)s * LPR + fid];
            float f[8];
            cvt8(v, f);
#pragma unroll
            for (int i = 0; i < 8; ++i) acc[i] += f[i] * c;
        }
    }
#pragma unroll
    for (int m = LPR; m < 64; m <<= 1) {
#pragma unroll
        for (int i = 0; i < 8; ++i) acc[i] += __shfl_xor(acc[i], m);
    }
    if (sub == 0) {
        const float4 bv0 = *(const float4*)&bias[fid * 8 + 0];
        const float4 bv1 = *(const float4*)&bias[fid * 8 + 4];
        float r[8];
        r[0] = fmaxf(acc[0] * d + bv0.x, 0.f);
        r[1] = fmaxf(acc[1] * d + bv0.y, 0.f);
        r[2] = fmaxf(acc[2] * d + bv0.z, 0.f);
        r[3] = fmaxf(acc[3] * d + bv0.w, 0.f);
        r[4] = fmaxf(acc[4] * d + bv1.x, 0.f);
        r[5] = fmaxf(acc[5] * d + bv1.y, 0.f);
        r[6] = fmaxf(acc[6] * d + bv1.z, 0.f);
        r[7] = fmaxf(acc[7] * d + bv1.w, 0.f);
        uint4 o;
        o.x = (unsigned)f2bf(r[0]) | ((unsigned)f2bf(r[1]) << 16);
        o.y = (unsigned)f2bf(r[2]) | ((unsigned)f2bf(r[3]) << 16);
        o.z = (unsigned)f2bf(r[4]) | ((unsigned)f2bf(r[5]) << 16);
        o.w = (unsigned)f2bf(r[6]) | ((unsigned)f2bf(r[7]) << 16);
        *(uint4*)&out[(size_t)n * NC + fid * 8] = o;
    }
}

// --- segment-mean pool helpers (batch is sorted) ---
__global__ __launch_bounds__(128) void pool_kernel(const float* __restrict__ a1,
                                                   const int* __restrict__ batch,
                                                   float* __restrict__ gsum, int N) {
    int f = threadIdx.x;
    int n0 = blockIdx.x * 128;
    int nend = min(n0 + 128, N);
    float acc = 0.f;
    int gcur = batch[n0];
    for (int n = n0; n < nend; ++n) {
        int g = batch[n];
        if (g != gcur) {
            atomicAdd(&gsum[gcur * 128 + f], acc);
            acc = 0.f;
            gcur = g;
        }
        acc += a1[(size_t)n * 128 + f];
    }
    atomicAdd(&gsum[gcur * 128 + f], acc);
}

__global__ __launch_bounds__(256) void count_batch_kernel(const int* __restrict__ batch,
                                                          int* __restrict__ gcnt, int N) {
    __shared__ int lc[64];
    int t = threadIdx.x;
    if (t < 64) lc[t] = 0;
    __syncthreads();
    int n = blockIdx.x * blockDim.x + t;
    if (n < N) atomicAdd(&lc[batch[n]], 1);
    __syncthreads();
    if (t < 64 && lc[t] > 0) atomicAdd(&gcnt[t], lc[t]);
}

__global__ __launch_bounds__(128) void finalize_kernel(const float* __restrict__ gsum,
                                                       const int* __restrict__ gcnt,
                                                       const float* __restrict__ Wf2,
                                                       const float* __restrict__ bf2,
                                                       float* __restrict__ out) {
    __shared__ float red0[128], red1[128];
    int g = blockIdx.x, f = threadIdx.x;
    float cntf = (float)max(gcnt[g], 1);
    float ge = gsum[g * 128 + f] / cntf;
    out[g * 128 + f] = ge;
    red0[f] = ge * Wf2[f * 2 + 0];
    red1[f] = ge * Wf2[f * 2 + 1];
    __syncthreads();
    for (int off = 64; off > 0; off >>= 1) {
        if (f < off) { red0[f] += red0[f + off]; red1[f] += red1[f + off]; }
        __syncthreads();
    }
    if (f == 0) {
        out[8192 + 1 + g * 2 + 0] = red0[0] + bf2[0];
        out[8192 + 1 + g * 2 + 1] = red1[0] + bf2[1];
        if (g == 0) out[8192] = 0.f;
    }
}

extern "C" void kernel_launch(void* const* d_in, const int* in_sizes, int n_in,
                              void* d_out, int out_size, void* d_ws, size_t ws_size,
                              hipStream_t stream) {
    const float* x   = (const float*)d_in[0];
    const float* W1  = (const float*)d_in[1];
    const float* b1  = (const float*)d_in[2];
    const float* W2  = (const float*)d_in[3];
    const float* b2  = (const float*)d_in[4];
    const float* Wf1 = (const float*)d_in[5];
    const float* bf1 = (const float*)d_in[6];
    const float* Wf2 = (const float*)d_in[7];
    const float* bf2 = (const float*)d_in[8];
    const int* edge  = (const int*)d_in[9];
    const int* batch = (const int*)d_in[10];

    const int N = in_sizes[10];      // 100000
    const int E = in_sizes[9] / 2;   // 3200000
    const int* srcA = edge;
    const int* dstA = edge + E;
    float* out = (float*)d_out;

    const int NB = (N + 511) >> 9;   // buckets of 512 nodes (196)

    char* p = (char*)d_ws;
    auto alloc = [&](size_t bytes) {
        char* r = p;
        p += (bytes + 255) & ~(size_t)255;
        return r;
    };
    float* gsum     = (float*)alloc(64 * 128 * 4);
    int*   gcnt     = (int*)alloc(64 * 4);
    int*   bcount   = (int*)alloc(256 * 4);
    int*   bfill    = (int*)alloc(256 * 4);
    size_t zbytes   = (size_t)(p - (char*)d_ws);
    int*   bstart   = (int*)alloc(260 * 4);
    float* dis      = (float*)alloc((size_t)N * 4);
    int*   rowstart = (int*)alloc((size_t)(N + 1) * 4);
    unsigned int* stage = (unsigned int*)alloc((size_t)E * 4);
    int*   csr_src  = (int*)alloc((size_t)E * 4);
    float* bufA     = (float*)alloc((size_t)N * 128 * 4);  // h/g (bf16) then a1 (f32)
    float* bufB     = (float*)alloc((size_t)N * 128 * 2);  // h1/h2 (bf16)

    unsigned short* bufAb = (unsigned short*)bufA;
    unsigned short* bufBb = (unsigned short*)bufB;

    hipMemsetAsync(d_ws, 0, zbytes, stream);

    const int EB = (E + 4095) / 4096;
    bucket_hist_kernel<<<EB, 256, 0, stream>>>(dstA, bcount, E);
    bucket_scan_kernel<<<1, 256, 0, stream>>>(bcount, bstart, rowstart, NB, N, E);
    bucket_scatter_kernel<<<EB, 256, 0, stream>>>(srcA, dstA, bstart, bfill, stage, E);
    csr_build_kernel<<<NB, 256, 0, stream>>>(stage, bstart, rowstart, dis, csr_src, N);

    // layer 1: h = x@W1 (bf16) ; h1 = relu(d*(sum dis_s*h_s + d*h_n) + b1) (bf16)
    gemm_kernel<128, 128, false, true><<<(N + 63) / 64, 256, 0, stream>>>(x, W1, nullptr,
                                                                          bufAb, N);
    aggregate_kernel<128><<<(N + 3) / 4, 256, 0, stream>>>(bufAb, dis, rowstart, csr_src,
                                                           b1, bufBb, N);
    // layer 2
    gemm_kernel<128, 64, true, true><<<(N + 63) / 64, 256, 0, stream>>>(bufBb, W2, nullptr,
                                                                        bufAb, N);
    aggregate_kernel<64><<<(N + 3) / 4, 256, 0, stream>>>(bufAb, dis, rowstart, csr_src,
                                                          b2, bufBb, N);
    // head: a1 = h2@Wf1 + bf1 (fp32)
    gemm_kernel<64, 128, true, false><<<(N + 63) / 64, 256, 0, stream>>>(bufBb, Wf1, bf1,
                                                                         bufA, N);

    pool_kernel<<<(N + 127) / 128, 128, 0, stream>>>(bufA, batch, gsum, N);
    count_batch_kernel<<<(N + 255) / 256, 256, 0, stream>>>(batch, gcnt, N);
    finalize_kernel<<<64, 128, 0, stream>>>(gsum, gcnt, Wf2, bf2, out);
}

// Round 5
// 548.946 us; speedup vs baseline: 1.9261x; 1.1985x over previous
//
#include <hip/hip_runtime.h>

// ---------------------------------------------------------------------------
// GCN forward, bf16 activations / fp32 weights+accum.
// CSR build via bucketed radix (bucket = dst>>9, 512 nodes/bucket).
// GEMMs: register-blocked outer-product fp32 (8x8 or 4x8 per thread),
// bf16-in/out variants via template. Then agg x2, head GEMM, pool.
// ---------------------------------------------------------------------------

__device__ __forceinline__ float bf2f(unsigned int lo16) {
    unsigned int v = lo16 << 16;
    return __builtin_bit_cast(float, v);
}
__device__ __forceinline__ unsigned short f2bf(float f) {
    unsigned int u = __builtin_bit_cast(unsigned int, f);
    u = (u + 0x7FFFu + ((u >> 16) & 1u)) >> 16;
    return (unsigned short)u;
}
__device__ __forceinline__ void cvt8(const uint4& v, float* f) {
    f[0] = bf2f(v.x & 0xFFFFu); f[1] = bf2f(v.x >> 16);
    f[2] = bf2f(v.y & 0xFFFFu); f[3] = bf2f(v.y >> 16);
    f[4] = bf2f(v.z & 0xFFFFu); f[5] = bf2f(v.z >> 16);
    f[6] = bf2f(v.w & 0xFFFFu); f[7] = bf2f(v.w >> 16);
}

// --- A1: bucket histogram (bucket = dst >> 9) ---
__global__ __launch_bounds__(256) void bucket_hist_kernel(const int* __restrict__ dst,
                                                          int* __restrict__ bcount, int E) {
    __shared__ int h[256];
    int t = threadIdx.x;
    h[t] = 0;
    __syncthreads();
    int base = blockIdx.x * 4096;
#pragma unroll
    for (int i = 0; i < 16; ++i) {
        int e = base + t + i * 256;
        if (e < E) atomicAdd(&h[dst[e] >> 9], 1);
    }
    __syncthreads();
    if (h[t] > 0) atomicAdd(&bcount[t], h[t]);
}

__global__ void bucket_scan_kernel(const int* __restrict__ bcount, int* __restrict__ bstart,
                                   int* __restrict__ rowstart, int NB, int N, int E) {
    __shared__ int s[256];
    int t = threadIdx.x;
    int v = (t < NB) ? bcount[t] : 0;
    s[t] = v;
    __syncthreads();
    for (int off = 1; off < 256; off <<= 1) {
        int tmp = 0;
        if (t >= off) tmp = s[t - off];
        __syncthreads();
        s[t] += tmp;
        __syncthreads();
    }
    bstart[t] = s[t] - v;
    if (t == 255) bstart[256] = s[255];
    if (t == 0) rowstart[N] = E;
}

// --- A2: stage packed (src | local_dst<<17) into bucket windows ---
__global__ __launch_bounds__(256) void bucket_scatter_kernel(const int* __restrict__ src,
                                                             const int* __restrict__ dst,
                                                             const int* __restrict__ bstart,
                                                             int* __restrict__ bfill,
                                                             unsigned int* __restrict__ stage,
                                                             int E) {
    __shared__ int hist[256];
    __shared__ int abase[256];
    int t = threadIdx.x;
    hist[t] = 0;
    __syncthreads();
    int base = blockIdx.x * 4096;
#pragma unroll
    for (int i = 0; i < 16; ++i) {
        int e = base + t + i * 256;
        if (e < E) atomicAdd(&hist[dst[e] >> 9], 1);
    }
    __syncthreads();
    if (hist[t] > 0) {
        int r = atomicAdd(&bfill[t], hist[t]);
        abase[t] = bstart[t] + r;
    }
    __syncthreads();
    hist[t] = 0;
    __syncthreads();
#pragma unroll
    for (int i = 0; i < 16; ++i) {
        int e = base + t + i * 256;
        if (e < E) {
            int d = dst[e];
            int b = d >> 9;
            int slot = atomicAdd(&hist[b], 1);
            stage[abase[b] + slot] = (unsigned)src[e] | ((unsigned)(d & 511) << 17);
        }
    }
}

// --- B: per-bucket CSR finalize ---
__global__ __launch_bounds__(256) void csr_build_kernel(const unsigned int* __restrict__ stage,
                                                        const int* __restrict__ bstart,
                                                        int* __restrict__ rowstart,
                                                        float* __restrict__ dis,
                                                        int* __restrict__ csr_src, int N) {
    __shared__ int cnt[512];
    __shared__ int ofs[512];
    __shared__ int psum[256];
    int b = blockIdx.x, t = threadIdx.x;
    int node0 = b << 9;
    int nb = min(512, N - node0);
    cnt[t] = 0;
    cnt[t + 256] = 0;
    __syncthreads();
    int eb = bstart[b], ee = bstart[b + 1];
    for (int e = eb + t; e < ee; e += 256) {
        unsigned w = stage[e];
        atomicAdd(&cnt[w >> 17], 1);
    }
    __syncthreads();
    int a = cnt[2 * t], c = cnt[2 * t + 1];
    int ps = a + c;
    psum[t] = ps;
    __syncthreads();
    for (int off = 1; off < 256; off <<= 1) {
        int tmp = 0;
        if (t >= off) tmp = psum[t - off];
        __syncthreads();
        psum[t] += tmp;
        __syncthreads();
    }
    int ex = psum[t] - ps;
    ofs[2 * t] = ex;
    ofs[2 * t + 1] = ex + a;
    if (2 * t < nb) {
        rowstart[node0 + 2 * t] = eb + ex;
        dis[node0 + 2 * t] = rsqrtf(1.f + (float)a);
    }
    if (2 * t + 1 < nb) {
        rowstart[node0 + 2 * t + 1] = eb + ex + a;
        dis[node0 + 2 * t + 1] = rsqrtf(1.f + (float)c);
    }
    __syncthreads();
    for (int e = eb + t; e < ee; e += 256) {
        unsigned w = stage[e];
        int l = w >> 17;
        int slot = atomicAdd(&ofs[l], 1);
        csr_src[eb + slot] = (int)(w & 0x1FFFFu);
    }
}

// --- register-blocked GEMM: C[M][NC] = X[M][K] @ W[K][NC] (+bias).
//     128-row x NC-col tile, 256 threads, 8 cols/thread, TM/RL rows/thread.
//     fp32 math; X may be bf16 (converted in staging), C may be bf16.
template <int K, int NC, bool IN_BF16, bool OUT_BF16>
__global__ __launch_bounds__(256) void gemm_kernel(const void* __restrict__ Xv,
                                                   const float* __restrict__ W,
                                                   const float* __restrict__ bias,
                                                   void* __restrict__ Cv, int M) {
    constexpr int TM = 128, KT = 32;
    constexpr int CL = NC / 8;      // col-lanes (16 or 8)
    constexpr int RL = 256 / CL;    // row-lanes (16 or 32)
    constexpr int RPT = TM / RL;    // rows per thread (8 or 4)
    constexpr int XSTR = KT + 1;    // 33: rows spread over banks
    constexpr int WSTR = NC + 12;   // skewed col groups

    __shared__ float XL[TM * XSTR];
    __shared__ float WL[KT * WSTR];

    int tid = threadIdx.x;
    int tx = tid % CL, ty = tid / CL;
    int rowBase = blockIdx.x * TM;

    // skewed offset for an 8-col group g: every bank covered exactly 2x
    const int wgo = tx * 8 + ((tx >> 2) << 2);

    float4 acc0[RPT], acc1[RPT];
#pragma unroll
    for (int i = 0; i < RPT; ++i) {
        acc0[i] = make_float4(0.f, 0.f, 0.f, 0.f);
        acc1[i] = make_float4(0.f, 0.f, 0.f, 0.f);
    }

    for (int kk = 0; kk < K; kk += KT) {
        // ---- stage X tile (scalar LDS writes; amortized over 32 k-steps) ----
        if (IN_BF16) {
            const unsigned short* Xb = (const unsigned short*)Xv;
#pragma unroll
            for (int q = 0; q < 2; ++q) {
                int li = q * 256 + tid;          // 512 uint4 chunks
                int r = li >> 2, c8 = (li & 3) * 8;
                int gr = rowBase + r;
                if (gr >= M) gr = M - 1;
                uint4 v = *(const uint4*)&Xb[(size_t)gr * K + kk + c8];
                float f[8];
                cvt8(v, f);
#pragma unroll
                for (int j = 0; j < 8; ++j) XL[r * XSTR + c8 + j] = f[j];
            }
        } else {
            const float* Xf = (const float*)Xv;
#pragma unroll
            for (int q = 0; q < 4; ++q) {
                int li = q * 256 + tid;          // 1024 float4 chunks
                int r = li >> 3, c4 = (li & 7) * 4;
                int gr = rowBase + r;
                if (gr >= M) gr = M - 1;
                float4 v = *(const float4*)&Xf[(size_t)gr * K + kk + c4];
                XL[r * XSTR + c4 + 0] = v.x;
                XL[r * XSTR + c4 + 1] = v.y;
                XL[r * XSTR + c4 + 2] = v.z;
                XL[r * XSTR + c4 + 3] = v.w;
            }
        }
        // ---- stage W tile (float4 LDS writes, skewed layout) ----
        constexpr int WCH = KT * NC / 4 / 256;   // float4 chunks per thread (4 or 2)
#pragma unroll
        for (int q = 0; q < WCH; ++q) {
            int li = q * 256 + tid;
            int k = li / (NC / 4), c = (li % (NC / 4)) * 4;
            int g = c >> 3;
            float4 v = *(const float4*)&W[(size_t)(kk + k) * NC + c];
            *(float4*)&WL[k * WSTR + g * 8 + ((g >> 2) << 2) + (c & 7)] = v;
        }
        __syncthreads();
        // ---- outer-product accumulate ----
#pragma unroll
        for (int k = 0; k < KT; ++k) {
            float4 w0 = *(const float4*)&WL[k * WSTR + wgo];
            float4 w1 = *(const float4*)&WL[k * WSTR + wgo + 4];
            float xv[RPT];
#pragma unroll
            for (int i = 0; i < RPT; ++i) xv[i] = XL[(ty * RPT + i) * XSTR + k];
#pragma unroll
            for (int i = 0; i < RPT; ++i) {
                acc0[i].x += xv[i] * w0.x; acc0[i].y += xv[i] * w0.y;
                acc0[i].z += xv[i] * w0.z; acc0[i].w += xv[i] * w0.w;
                acc1[i].x += xv[i] * w1.x; acc1[i].y += xv[i] * w1.y;
                acc1[i].z += xv[i] * w1.z; acc1[i].w += xv[i] * w1.w;
            }
        }
        __syncthreads();
    }

    float4 b0 = make_float4(0.f, 0.f, 0.f, 0.f), b1 = b0;
    if (bias) {
        b0 = *(const float4*)&bias[tx * 8];
        b1 = *(const float4*)&bias[tx * 8 + 4];
    }
#pragma unroll
    for (int i = 0; i < RPT; ++i) {
        int gr = rowBase + ty * RPT + i;
        if (gr < M) {
            float4 v0 = acc0[i], v1 = acc1[i];
            v0.x += b0.x; v0.y += b0.y; v0.z += b0.z; v0.w += b0.w;
            v1.x += b1.x; v1.y += b1.y; v1.z += b1.z; v1.w += b1.w;
            if (OUT_BF16) {
                unsigned short* Cb = (unsigned short*)Cv;
                uint4 o;
                o.x = (unsigned)f2bf(v0.x) | ((unsigned)f2bf(v0.y) << 16);
                o.y = (unsigned)f2bf(v0.z) | ((unsigned)f2bf(v0.w) << 16);
                o.z = (unsigned)f2bf(v1.x) | ((unsigned)f2bf(v1.y) << 16);
                o.w = (unsigned)f2bf(v1.z) | ((unsigned)f2bf(v1.w) << 16);
                *(uint4*)&Cb[(size_t)gr * NC + tx * 8] = o;
            } else {
                float* Cf = (float*)Cv;
                *(float4*)&Cf[(size_t)gr * NC + tx * 8] = v0;
                *(float4*)&Cf[(size_t)gr * NC + tx * 8 + 4] = v1;
            }
        }
    }
}

// --- wave-per-node bf16 gather aggregation (fp32 accum) ---
template <int NC>
__global__ __launch_bounds__(256) void aggregate_kernel(const unsigned short* __restrict__ h,
                                                        const float* __restrict__ dis,
                                                        const int* __restrict__ rowstart,
                                                        const int* __restrict__ csr_src,
                                                        const float* __restrict__ bias,
                                                        unsigned short* __restrict__ out,
                                                        int N) {
    constexpr int LPR = NC / 8;   // lanes per row (16B = 8 bf16 each)
    constexpr int RPS = 64 / LPR; // rows (edges) per step
    int wid = (blockIdx.x * blockDim.x + threadIdx.x) >> 6;
    int lane = threadIdx.x & 63;
    if (wid >= N) return;
    int n = wid;
    int sub = lane / LPR;
    int fid = lane % LPR;
    const uint4* h4 = (const uint4*)h;
    float d = dis[n];
    float acc[8];
#pragma unroll
    for (int i = 0; i < 8; ++i) acc[i] = 0.f;
    if (sub == 0) {
        uint4 hv = h4[(size_t)n * LPR + fid];
        float f[8];
        cvt8(hv, f);
#pragma unroll
        for (int i = 0; i < 8; ++i) acc[i] = f[i] * d;
    }

    int beg = rowstart[n], end = rowstart[n + 1];
    for (int e0 = beg; e0 < end; e0 += 64) {
        int idx = e0 + lane;
        int sv = 0;
        float dv = 0.f;
        if (idx < end) { sv = csr_src[idx]; dv = dis[sv]; }
        int cnt = min(64, end - e0);
        int j = 0;
        for (; j + 2 * RPS <= cnt; j += 2 * RPS) {
            int ja = j + sub, jb = j + RPS + sub;
            int sa = __shfl(sv, ja); float ca = __shfl(dv, ja);
            int sb = __shfl(sv, jb); float cb = __shfl(dv, jb);
            uint4 va = h4[(size_t)sa * LPR + fid];
            uint4 vb = h4[(size_t)sb * LPR + fid];
            float fa[8], fb[8];
            cvt8(va, fa);
            cvt8(vb, fb);
#pragma unroll
            for (int i = 0; i < 8; ++i) acc[i] += fa[i] * ca + fb[i] * cb;
        }
        for (; j < cnt; j += RPS) {
            int jj = j + sub;
            int jc = min(jj, cnt - 1);
            int s = __shfl(sv, jc);
            float c = __shfl(dv, jc);
            if (jj >= cnt) c = 0.f;
            uint4 v = h4[(size_t)s * LPR + fid];
            float f[8];
            cvt8(v, f);
#pragma unroll
            for (int i = 0; i < 8; ++i) acc[i] += f[i] * c;
        }
    }
#pragma unroll
    for (int m = LPR; m < 64; m <<= 1) {
#pragma unroll
        for (int i = 0; i < 8; ++i) acc[i] += __shfl_xor(acc[i], m);
    }
    if (sub == 0) {
        const float4 bv0 = *(const float4*)&bias[fid * 8 + 0];
        const float4 bv1 = *(const float4*)&bias[fid * 8 + 4];
        float r[8];
        r[0] = fmaxf(acc[0] * d + bv0.x, 0.f);
        r[1] = fmaxf(acc[1] * d + bv0.y, 0.f);
        r[2] = fmaxf(acc[2] * d + bv0.z, 0.f);
        r[3] = fmaxf(acc[3] * d + bv0.w, 0.f);
        r[4] = fmaxf(acc[4] * d + bv1.x, 0.f);
        r[5] = fmaxf(acc[5] * d + bv1.y, 0.f);
        r[6] = fmaxf(acc[6] * d + bv1.z, 0.f);
        r[7] = fmaxf(acc[7] * d + bv1.w, 0.f);
        uint4 o;
        o.x = (unsigned)f2bf(r[0]) | ((unsigned)f2bf(r[1]) << 16);
        o.y = (unsigned)f2bf(r[2]) | ((unsigned)f2bf(r[3]) << 16);
        o.z = (unsigned)f2bf(r[4]) | ((unsigned)f2bf(r[5]) << 16);
        o.w = (unsigned)f2bf(r[6]) | ((unsigned)f2bf(r[7]) << 16);
        *(uint4*)&out[(size_t)n * NC + fid * 8] = o;
    }
}

// --- segment-mean pool helpers (batch is sorted) ---
__global__ __launch_bounds__(128) void pool_kernel(const float* __restrict__ a1,
                                                   const int* __restrict__ batch,
                                                   float* __restrict__ gsum, int N) {
    int f = threadIdx.x;
    int n0 = blockIdx.x * 128;
    int nend = min(n0 + 128, N);
    float acc = 0.f;
    int gcur = batch[n0];
    for (int n = n0; n < nend; ++n) {
        int g = batch[n];
        if (g != gcur) {
            atomicAdd(&gsum[gcur * 128 + f], acc);
            acc = 0.f;
            gcur = g;
        }
        acc += a1[(size_t)n * 128 + f];
    }
    atomicAdd(&gsum[gcur * 128 + f], acc);
}

__global__ __launch_bounds__(256) void count_batch_kernel(const int* __restrict__ batch,
                                                          int* __restrict__ gcnt, int N) {
    __shared__ int lc[64];
    int t = threadIdx.x;
    if (t < 64) lc[t] = 0;
    __syncthreads();
    int n = blockIdx.x * blockDim.x + t;
    if (n < N) atomicAdd(&lc[batch[n]], 1);
    __syncthreads();
    if (t < 64 && lc[t] > 0) atomicAdd(&gcnt[t], lc[t]);
}

__global__ __launch_bounds__(128) void finalize_kernel(const float* __restrict__ gsum,
                                                       const int* __restrict__ gcnt,
                                                       const float* __restrict__ Wf2,
                                                       const float* __restrict__ bf2,
                                                       float* __restrict__ out) {
    __shared__ float red0[128], red1[128];
    int g = blockIdx.x, f = threadIdx.x;
    float cntf = (float)max(gcnt[g], 1);
    float ge = gsum[g * 128 + f] / cntf;
    out[g * 128 + f] = ge;
    red0[f] = ge * Wf2[f * 2 + 0];
    red1[f] = ge * Wf2[f * 2 + 1];
    __syncthreads();
    for (int off = 64; off > 0; off >>= 1) {
        if (f < off) { red0[f] += red0[f + off]; red1[f] += red1[f + off]; }
        __syncthreads();
    }
    if (f == 0) {
        out[8192 + 1 + g * 2 + 0] = red0[0] + bf2[0];
        out[8192 + 1 + g * 2 + 1] = red1[0] + bf2[1];
        if (g == 0) out[8192] = 0.f;
    }
}

extern "C" void kernel_launch(void* const* d_in, const int* in_sizes, int n_in,
                              void* d_out, int out_size, void* d_ws, size_t ws_size,
                              hipStream_t stream) {
    const float* x   = (const float*)d_in[0];
    const float* W1  = (const float*)d_in[1];
    const float* b1  = (const float*)d_in[2];
    const float* W2  = (const float*)d_in[3];
    const float* b2  = (const float*)d_in[4];
    const float* Wf1 = (const float*)d_in[5];
    const float* bf1 = (const float*)d_in[6];
    const float* Wf2 = (const float*)d_in[7];
    const float* bf2 = (const float*)d_in[8];
    const int* edge  = (const int*)d_in[9];
    const int* batch = (const int*)d_in[10];

    const int N = in_sizes[10];      // 100000
    const int E = in_sizes[9] / 2;   // 3200000
    const int* srcA = edge;
    const int* dstA = edge + E;
    float* out = (float*)d_out;

    const int NB = (N + 511) >> 9;   // buckets of 512 nodes

    char* p = (char*)d_ws;
    auto alloc = [&](size_t bytes) {
        char* r = p;
        p += (bytes + 255) & ~(size_t)255;
        return r;
    };
    float* gsum     = (float*)alloc(64 * 128 * 4);
    int*   gcnt     = (int*)alloc(64 * 4);
    int*   bcount   = (int*)alloc(256 * 4);
    int*   bfill    = (int*)alloc(256 * 4);
    size_t zbytes   = (size_t)(p - (char*)d_ws);
    int*   bstart   = (int*)alloc(260 * 4);
    float* dis      = (float*)alloc((size_t)N * 4);
    int*   rowstart = (int*)alloc((size_t)(N + 1) * 4);
    unsigned int* stage = (unsigned int*)alloc((size_t)E * 4);
    int*   csr_src  = (int*)alloc((size_t)E * 4);
    float* bufA     = (float*)alloc((size_t)N * 128 * 4);  // h/g (bf16) then a1 (f32)
    float* bufB     = (float*)alloc((size_t)N * 128 * 2);  // h1/h2 (bf16)

    unsigned short* bufAb = (unsigned short*)bufA;
    unsigned short* bufBb = (unsigned short*)bufB;

    hipMemsetAsync(d_ws, 0, zbytes, stream);

    const int EB = (E + 4095) / 4096;
    bucket_hist_kernel<<<EB, 256, 0, stream>>>(dstA, bcount, E);
    bucket_scan_kernel<<<1, 256, 0, stream>>>(bcount, bstart, rowstart, NB, N, E);
    bucket_scatter_kernel<<<EB, 256, 0, stream>>>(srcA, dstA, bstart, bfill, stage, E);
    csr_build_kernel<<<NB, 256, 0, stream>>>(stage, bstart, rowstart, dis, csr_src, N);

    const int GB = (N + 127) / 128;
    // layer 1: h = x@W1 (bf16) ; h1 = relu(d*(sum dis_s*h_s + d*h_n) + b1) (bf16)
    gemm_kernel<128, 128, false, true><<<GB, 256, 0, stream>>>(x, W1, nullptr, bufAb, N);
    aggregate_kernel<128><<<(N + 3) / 4, 256, 0, stream>>>(bufAb, dis, rowstart, csr_src,
                                                           b1, bufBb, N);
    // layer 2
    gemm_kernel<128, 64, true, true><<<GB, 256, 0, stream>>>(bufBb, W2, nullptr, bufAb, N);
    aggregate_kernel<64><<<(N + 3) / 4, 256, 0, stream>>>(bufAb, dis, rowstart, csr_src,
                                                          b2, bufBb, N);
    // head: a1 = h2@Wf1 + bf1 (fp32)
    gemm_kernel<64, 128, true, false><<<GB, 256, 0, stream>>>(bufBb, Wf1, bf1, bufA, N);

    pool_kernel<<<(N + 127) / 128, 128, 0, stream>>>(bufA, batch, gsum, N);
    count_batch_kernel<<<(N + 255) / 256, 256, 0, stream>>>(batch, gcnt, N);
    finalize_kernel<<<64, 128, 0, stream>>>(gsum, gcnt, Wf2, bf2, out);
}